// Round 1
// baseline (673.554 us; speedup 1.0000x reference)
//
#include <hip/hip_runtime.h>
#include <stdint.h>

#define IN_F 4096
#define OUT_F 4096
#define SEQ 8192          // 4 * 2048 tokens
#define NTRI 2016

typedef __attribute__((ext_vector_type(8))) short short8;
typedef __attribute__((ext_vector_type(4))) float f32x4;

__device__ __forceinline__ unsigned short f2bf(float f) {
    uint32_t u = __builtin_bit_cast(uint32_t, f);
    u = (u + 0x7FFFu + ((u >> 16) & 1u)) >> 16;   // round-to-nearest-even
    return (unsigned short)u;
}

__device__ __forceinline__ void gload16(const void* g, void* l) {
    __builtin_amdgcn_global_load_lds((__attribute__((address_space(1))) void*)g,
                                     (__attribute__((address_space(3))) void*)l,
                                     16, 0, 0);
}

// ---------------- pass 1: invert perm_in_inv -> pin ----------------
__global__ void k_inv_perm(const int* __restrict__ perm_in_inv, int* __restrict__ pin) {
    int i = blockIdx.x * 256 + threadIdx.x;
    if (i < IN_F) pin[perm_in_inv[i]] = i;
}

// ---------------- pass 2: Cayley-Neumann R = I + 2(Q+Q^2+Q^3+Q^4) ----------------
__global__ __launch_bounds__(256) void k_cayley(const float* __restrict__ Ro,
                                                const float* __restrict__ Ri,
                                                float* __restrict__ Rout,
                                                float* __restrict__ Rin) {
    __shared__ float Qs[4096];
    __shared__ float Ps[4096];
    __shared__ float Ts[4096];
    int b = blockIdx.x;  // 0..127 : first 64 = Ro blocks, next 64 = Ri blocks
    const float* vec = (b < 64) ? (Ro + (size_t)b * NTRI) : (Ri + (size_t)(b - 64) * NTRI);
    float* dst = (b < 64) ? (Rout + (size_t)b * 4096) : (Rin + (size_t)(b - 64) * 4096);
    int t = threadIdx.x;
    float acc[16];
#pragma unroll
    for (int e = 0; e < 16; ++e) {
        int el = e * 256 + t;
        int i = el >> 6, j = el & 63;
        float q = 0.f;
        if (i < j) q =  vec[i * 63 - (i * (i - 1)) / 2 + (j - i - 1)];
        if (i > j) q = -vec[j * 63 - (j * (j - 1)) / 2 + (i - j - 1)];
        Qs[el] = q;
        acc[e] = q;
    }
    __syncthreads();
    // Q^2 -> Ps
#pragma unroll
    for (int e = 0; e < 16; ++e) {
        int el = e * 256 + t;
        int i = el >> 6, j = el & 63;
        float s = 0.f;
        for (int k = 0; k < 64; ++k) s += Qs[i * 64 + k] * Qs[k * 64 + j];
        Ps[el] = s; acc[e] += s;
    }
    __syncthreads();
    // Q^3 -> Ts
#pragma unroll
    for (int e = 0; e < 16; ++e) {
        int el = e * 256 + t;
        int i = el >> 6, j = el & 63;
        float s = 0.f;
        for (int k = 0; k < 64; ++k) s += Ps[i * 64 + k] * Qs[k * 64 + j];
        Ts[el] = s; acc[e] += s;
    }
    __syncthreads();
    // Q^4 (no store) and final R
#pragma unroll
    for (int e = 0; e < 16; ++e) {
        int el = e * 256 + t;
        int i = el >> 6, j = el & 63;
        float s = 0.f;
        for (int k = 0; k < 64; ++k) s += Ts[i * 64 + k] * Qs[k * 64 + j];
        acc[e] += s;
        dst[el] = 2.f * acc[e] + ((i == j) ? 1.f : 0.f);
    }
}

// ---------------- pass 3: bias' = bias . R_out_bd ----------------
__global__ void k_bias_rot(const float* __restrict__ bias, const float* __restrict__ Rout,
                           float* __restrict__ bias_prime) {
    int r = blockIdx.x;   // 64
    int d = threadIdx.x;  // 64
    const float* Rb = Rout + (size_t)r * 4096;
    float s = 0.f;
    for (int c = 0; c < 64; ++c) s += bias[r * 64 + c] * Rb[c * 64 + d];
    bias_prime[r * 64 + d] = s;
}

// ---------------- pass 4: fold  Ct[o][i] = (R_in_bd W^T R_out_bd)[i][o]  (bf16) -------------
__global__ __launch_bounds__(256) void k_fold(const float* __restrict__ W,
                                              const float* __restrict__ Rin,
                                              const float* __restrict__ Rout,
                                              unsigned short* __restrict__ Ct) {
    __shared__ float Wb[4096];    // [c][b] = W[r*64+c][s*64+b]
    __shared__ float RoS[4096];   // [c][d]
    __shared__ float RiT[4096];   // [b][a] = Rin[s][a][b]
    __shared__ float Ud[4096];    // [d][b]
    int s = blockIdx.x;
    int r = blockIdx.y;
    int t = threadIdx.x;
#pragma unroll
    for (int e = 0; e < 16; ++e) {
        int el = e * 256 + t;
        int hi = el >> 6, lo = el & 63;
        Wb[el]  = W[(size_t)(r * 64 + hi) * IN_F + s * 64 + lo];
        RoS[el] = Rout[(size_t)r * 4096 + el];
        RiT[el] = Rin[(size_t)s * 4096 + lo * 64 + hi];   // transpose on load
    }
    __syncthreads();
    // Ud[d][b] = sum_c Wb[c][b] * RoS[c][d]
#pragma unroll
    for (int e = 0; e < 16; ++e) {
        int el = e * 256 + t;
        int d = el >> 6, b2 = el & 63;
        float acc = 0.f;
        for (int c = 0; c < 64; ++c) acc += Wb[c * 64 + b2] * RoS[c * 64 + d];
        Ud[el] = acc;  // el == d*64+b2
    }
    __syncthreads();
    // T[a][d] = sum_b RiT[b][a] * Ud[d][b]; store transposed tile into Ct
#pragma unroll
    for (int e = 0; e < 16; ++e) {
        int el = e * 256 + t;
        int d = el >> 6, a = el & 63;
        float acc = 0.f;
        for (int b2 = 0; b2 < 64; ++b2) acc += RiT[b2 * 64 + a] * Ud[d * 64 + b2];
        Ct[(size_t)(r * 64 + d) * IN_F + s * 64 + a] = f2bf(acc);
    }
}

// ---------------- pass 5: apply both permutations -> Mt[j][k] = C[pin[k]][pout[j]] --------
__global__ __launch_bounds__(256) void k_permM(const unsigned short* __restrict__ Ct,
                                               const int* __restrict__ pout,
                                               const int* __restrict__ pin,
                                               unsigned short* __restrict__ Mt) {
    __shared__ unsigned short row[4096];
    int j = blockIdx.x;
    int t = threadIdx.x;
    const unsigned short* sr = Ct + (size_t)pout[j] * IN_F;
#pragma unroll
    for (int e = 0; e < 16; ++e) row[e * 256 + t] = sr[e * 256 + t];
    __syncthreads();
    unsigned short* dr = Mt + (size_t)j * IN_F;
#pragma unroll
    for (int e = 0; e < 16; ++e) {
        int k = e * 256 + t;
        dr[k] = row[pin[k]];
    }
}

// ---------------- pass 6: bias_final[j] = bias'[pout[j]] ----------------
__global__ void k_bias_perm(const float* __restrict__ bias_prime, const int* __restrict__ pout,
                            float* __restrict__ bias_final) {
    int j = blockIdx.x * 256 + threadIdx.x;
    if (j < OUT_F) bias_final[j] = bias_prime[pout[j]];
}

// ---------------- pass 7: x -> bf16 (streaming cast) ----------------
__global__ __launch_bounds__(256) void k_xcast(const float* __restrict__ x,
                                               unsigned short* __restrict__ xb) {
    size_t idx = ((size_t)blockIdx.x * 256 + threadIdx.x) * 8;
    const f32x4* xp = (const f32x4*)(x + idx);
    f32x4 a = xp[0], b = xp[1];
    union { short8 v; unsigned short s[8]; } o;
    o.s[0] = f2bf(a[0]); o.s[1] = f2bf(a[1]); o.s[2] = f2bf(a[2]); o.s[3] = f2bf(a[3]);
    o.s[4] = f2bf(b[0]); o.s[5] = f2bf(b[1]); o.s[6] = f2bf(b[2]); o.s[7] = f2bf(b[3]);
    *(short8*)(xb + idx) = o.v;
}

// ---------------- pass 8: out = xb @ Mt^T + bias  (bf16 MFMA, 128x128 tile) ----------------
__global__ __launch_bounds__(256) void k_gemm(const unsigned short* __restrict__ A,   // [8192][4096]
                                              const unsigned short* __restrict__ Bt,  // [4096][4096] N-major
                                              const float* __restrict__ bias,
                                              float* __restrict__ out) {
    __shared__ __align__(16) unsigned short As[128 * 32];
    __shared__ __align__(16) unsigned short Bs[128 * 32];
    int t = threadIdx.x;
    int lane = t & 63;
    int w = t >> 6;
    int wr = w >> 1, wc = w & 1;
    int bx = blockIdx.x;   // N tile: 0..31
    int by = blockIdx.y;   // M tile: 0..63

    int row_ld = t >> 2;             // 0..63
    int kof = (t & 3) * 8;           // 0,8,16,24
    const unsigned short* gA0 = A  + (size_t)(by * 128 + row_ld) * IN_F + kof;
    const unsigned short* gA1 = gA0 + (size_t)64 * IN_F;
    const unsigned short* gB0 = Bt + (size_t)(bx * 128 + row_ld) * IN_F + kof;
    const unsigned short* gB1 = gB0 + (size_t)64 * IN_F;
    unsigned short* lA0 = As + t * 8;
    unsigned short* lA1 = As + 2048 + t * 8;
    unsigned short* lB0 = Bs + t * 8;
    unsigned short* lB1 = Bs + 2048 + t * 8;

    int frow = lane & 15;
    int fkof = (lane >> 4) * 8;
    const unsigned short* pa = As + (wr * 64 + frow) * 32 + fkof;
    const unsigned short* pb = Bs + (wc * 64 + frow) * 32 + fkof;

    f32x4 acc[4][4];
#pragma unroll
    for (int m = 0; m < 4; ++m)
#pragma unroll
        for (int n = 0; n < 4; ++n) acc[m][n] = f32x4{0.f, 0.f, 0.f, 0.f};

    for (int kt = 0; kt < IN_F / 32; ++kt) {
        __syncthreads();   // previous iter's LDS reads complete before overwrite
        gload16(gA0 + kt * 32, lA0);
        gload16(gA1 + kt * 32, lA1);
        gload16(gB0 + kt * 32, lB0);
        gload16(gB1 + kt * 32, lB1);
        __syncthreads();   // staging complete (vmcnt drained by barrier)
        short8 af[4], bf[4];
#pragma unroll
        for (int m = 0; m < 4; ++m) af[m] = *(const short8*)(pa + m * 512);
#pragma unroll
        for (int n = 0; n < 4; ++n) bf[n] = *(const short8*)(pb + n * 512);
#pragma unroll
        for (int m = 0; m < 4; ++m)
#pragma unroll
            for (int n = 0; n < 4; ++n)
                acc[m][n] = __builtin_amdgcn_mfma_f32_16x16x32_bf16(af[m], bf[n], acc[m][n], 0, 0, 0);
    }

    int col0 = bx * 128 + wc * 64 + (lane & 15);
    int row0 = by * 128 + wr * 64 + (lane >> 4) * 4;
    float bv[4];
#pragma unroll
    for (int n = 0; n < 4; ++n) bv[n] = bias[col0 + n * 16];
#pragma unroll
    for (int m = 0; m < 4; ++m)
#pragma unroll
        for (int n = 0; n < 4; ++n)
#pragma unroll
            for (int i = 0; i < 4; ++i)
                out[(size_t)(row0 + m * 16 + i) * OUT_F + col0 + n * 16] = acc[m][n][i] + bv[n];
}

extern "C" void kernel_launch(void* const* d_in, const int* in_sizes, int n_in,
                              void* d_out, int out_size, void* d_ws, size_t ws_size,
                              hipStream_t stream) {
    (void)in_sizes; (void)n_in; (void)out_size; (void)ws_size;
    const float* x    = (const float*)d_in[0];
    const float* Ro   = (const float*)d_in[1];
    const float* Ri   = (const float*)d_in[2];
    const float* W    = (const float*)d_in[3];
    const float* bias = (const float*)d_in[4];
    const int* perm_in_inv = (const int*)d_in[5];
    const int* perm_out    = (const int*)d_in[6];
    float* out = (float*)d_out;

    char* ws = (char*)d_ws;
    float* Rout   = (float*)(ws);                         // 1 MiB
    float* Rin    = (float*)(ws + (1ull << 20));          // 1 MiB
    int*   pin    = (int*)(ws + (2ull << 20));            // 16 KiB
    float* bprime = (float*)(ws + (2ull << 20) + (1 << 14));
    float* bfinal = (float*)(ws + (2ull << 20) + (2 << 14));
    unsigned short* Mt = (unsigned short*)(ws + (4ull << 20));    // 32 MiB
    unsigned short* xb = (unsigned short*)(ws + (36ull << 20));   // 64 MiB
    unsigned short* Ct = (unsigned short*)(ws + (68ull << 20));   // 32 MiB (aliases xb tail; Ct consumed before xb written)

    k_inv_perm<<<16, 256, 0, stream>>>(perm_in_inv, pin);
    k_cayley<<<128, 256, 0, stream>>>(Ro, Ri, Rout, Rin);
    k_bias_rot<<<64, 64, 0, stream>>>(bias, Rout, bprime);
    k_fold<<<dim3(64, 64), 256, 0, stream>>>(W, Rin, Rout, Ct);
    k_permM<<<4096, 256, 0, stream>>>(Ct, perm_out, pin, Mt);
    k_bias_perm<<<16, 256, 0, stream>>>(bprime, perm_out, bfinal);
    k_xcast<<<16384, 256, 0, stream>>>(x, xb);
    k_gemm<<<dim3(32, 64), 256, 0, stream>>>(xb, Mt, bfinal, out);
}

// Round 2
// 369.320 us; speedup vs baseline: 1.8238x; 1.8238x over previous
//
#include <hip/hip_runtime.h>
#include <stdint.h>

#define IN_F 4096
#define OUT_F 4096
#define NTRI 2016

typedef unsigned short u16;
typedef __attribute__((ext_vector_type(8))) short short8;
typedef __attribute__((ext_vector_type(4))) float f32x4;
typedef __attribute__((ext_vector_type(4))) unsigned short u16x4;

__device__ __forceinline__ u16 f2bf(float f) {
    uint32_t u = __builtin_bit_cast(uint32_t, f);
    u = (u + 0x7FFFu + ((u >> 16) & 1u)) >> 16;   // round-to-nearest-even
    return (u16)u;
}

__device__ __forceinline__ void gload16(const void* g, void* l) {
    __builtin_amdgcn_global_load_lds((__attribute__((address_space(1))) void*)g,
                                     (__attribute__((address_space(3))) void*)l,
                                     16, 0, 0);
}

// ---------------- pass 1: invert perm_in_inv -> pin ----------------
__global__ void k_inv_perm(const int* __restrict__ perm_in_inv, int* __restrict__ pin) {
    int i = blockIdx.x * 256 + threadIdx.x;
    if (i < IN_F) pin[perm_in_inv[i]] = i;
}

// ---------------- pass 2: Cayley-Neumann, 4x4 register-blocked ----------------
// blocks 0..63 -> Rout[b] (row-major). blocks 64..127 -> RinT[b-64] (transposed).
// Uses skew/symmetry so every LDS read is a row-read:
//   Q^2[i][j] = -sum_k Q[k][i]Q[k][j]   (Q skew)
//   Q^3[i][j] =  sum_k Q2[k][i]Q[k][j]  (Q2 symmetric)
//   Q^4[i][j] = -sum_k T[k][i]Q[k][j],  T[k][i] := Q3[k][i] (stored via skew flip)
__global__ __launch_bounds__(256) void k_cayley(const float* __restrict__ Ro,
                                                const float* __restrict__ Ri,
                                                float* __restrict__ Rout,
                                                float* __restrict__ RinT) {
    __shared__ __align__(16) float Qs[64 * 64];
    __shared__ __align__(16) float Ps[64 * 68];
    __shared__ __align__(16) float Ts[64 * 68];
    int b = blockIdx.x;
    const float* vec = (b < 64) ? (Ro + (size_t)b * NTRI) : (Ri + (size_t)(b - 64) * NTRI);
    int t = threadIdx.x;
    int tr = t >> 4, tc = t & 15;
#pragma unroll
    for (int e = 0; e < 16; ++e) {
        int el = e * 256 + t;
        int i = el >> 6, j = el & 63;
        float q = 0.f;
        if (i < j) q =  vec[i * 63 - (i * (i - 1)) / 2 + (j - i - 1)];
        if (i > j) q = -vec[j * 63 - (j * (j - 1)) / 2 + (i - j - 1)];
        Qs[el] = q;
    }
    __syncthreads();
    float a2[4][4], a3[4][4], a4[4][4];
#pragma unroll
    for (int i = 0; i < 4; ++i)
#pragma unroll
        for (int j = 0; j < 4; ++j) { a2[i][j] = 0.f; a3[i][j] = 0.f; a4[i][j] = 0.f; }
    for (int k = 0; k < 64; ++k) {
        f32x4 qa = *(const f32x4*)&Qs[k * 64 + tr * 4];
        f32x4 qb = *(const f32x4*)&Qs[k * 64 + tc * 4];
#pragma unroll
        for (int i = 0; i < 4; ++i)
#pragma unroll
            for (int j = 0; j < 4; ++j) a2[i][j] -= qa[i] * qb[j];
    }
#pragma unroll
    for (int i = 0; i < 4; ++i)
#pragma unroll
        for (int j = 0; j < 4; ++j) Ps[(tr * 4 + i) * 68 + tc * 4 + j] = a2[i][j];
    __syncthreads();
    for (int k = 0; k < 64; ++k) {
        f32x4 pa = *(const f32x4*)&Ps[k * 68 + tr * 4];
        f32x4 qb = *(const f32x4*)&Qs[k * 64 + tc * 4];
#pragma unroll
        for (int i = 0; i < 4; ++i)
#pragma unroll
            for (int j = 0; j < 4; ++j) a3[i][j] += pa[i] * qb[j];
    }
#pragma unroll
    for (int i = 0; i < 4; ++i)
#pragma unroll
        for (int j = 0; j < 4; ++j) Ts[(tc * 4 + j) * 68 + tr * 4 + i] = -a3[i][j];  // Ts[k][i]=Q3[k][i]
    __syncthreads();
    for (int k = 0; k < 64; ++k) {
        f32x4 ta = *(const f32x4*)&Ts[k * 68 + tr * 4];
        f32x4 qb = *(const f32x4*)&Qs[k * 64 + tc * 4];
#pragma unroll
        for (int i = 0; i < 4; ++i)
#pragma unroll
            for (int j = 0; j < 4; ++j) a4[i][j] -= ta[i] * qb[j];
    }
    if (b < 64) {
        float* dst = Rout + (size_t)b * 4096;
#pragma unroll
        for (int i = 0; i < 4; ++i) {
            int gi = tr * 4 + i;
            f32x4 q4 = *(const f32x4*)&Qs[gi * 64 + tc * 4];
            f32x4 o;
#pragma unroll
            for (int j = 0; j < 4; ++j) {
                int gj = tc * 4 + j;
                float v = 2.f * (q4[j] + a2[i][j] + a3[i][j] + a4[i][j]) + ((gi == gj) ? 1.f : 0.f);
                o[j] = v;
            }
            *(f32x4*)&dst[gi * 64 + tc * 4] = o;
        }
    } else {
        float* dstT = RinT + (size_t)(b - 64) * 4096;
#pragma unroll
        for (int i = 0; i < 4; ++i) {
            int gi = tr * 4 + i;
            f32x4 q4 = *(const f32x4*)&Qs[gi * 64 + tc * 4];
#pragma unroll
            for (int j = 0; j < 4; ++j) {
                int gj = tc * 4 + j;
                float v = 2.f * (q4[j] + a2[i][j] + a3[i][j] + a4[i][j]) + ((gi == gj) ? 1.f : 0.f);
                dstT[gj * 64 + gi] = v;   // RinT[b][a] = R[a][b]
            }
        }
    }
}

// ---------------- pass 3: bias' = bias . R_out_bd ----------------
__global__ void k_bias_rot(const float* __restrict__ bias, const float* __restrict__ Rout,
                           float* __restrict__ bias_prime) {
    int r = blockIdx.x;
    int d = threadIdx.x;
    const float* Rb = Rout + (size_t)r * 4096;
    float s = 0.f;
    for (int c = 0; c < 64; ++c) s += bias[r * 64 + c] * Rb[c * 64 + d];
    bias_prime[r * 64 + d] = s;
}

// ---------------- pass 4: fold  Ct[o][i] = (R_in_bd W^T R_out_bd)[i][o]  (bf16) -----------
// 4x4 register-blocked: mm1 Ud[d][b]=sum_c W[rc][sb]*Rout[c][d]; mm2 T[a][d]=sum_b RinT[b][a]*Ud[d][b]
__global__ __launch_bounds__(256) void k_fold(const float* __restrict__ W,
                                              const float* __restrict__ RinT,
                                              const float* __restrict__ Rout,
                                              u16* __restrict__ Ct) {
    __shared__ __align__(16) float Wb[64 * 64];    // [c][b]
    __shared__ __align__(16) float RoS[64 * 64];   // [c][d]
    __shared__ __align__(16) float RiTs[64 * 64];  // [b][a]
    __shared__ __align__(16) float UdT[64 * 68];   // [b][d] padded
    int s = blockIdx.x;
    int r = blockIdx.y;
    int t = threadIdx.x;
    int tr = t >> 4, tc = t & 15;
#pragma unroll
    for (int e = 0; e < 16; ++e) {
        int el = e * 256 + t;
        int hi = el >> 6, lo = el & 63;
        Wb[el]   = W[(size_t)(r * 64 + hi) * IN_F + s * 64 + lo];
        RoS[el]  = Rout[(size_t)r * 4096 + el];
        RiTs[el] = RinT[(size_t)s * 4096 + el];
    }
    __syncthreads();
    float a1[4][4];
#pragma unroll
    for (int i = 0; i < 4; ++i)
#pragma unroll
        for (int j = 0; j < 4; ++j) a1[i][j] = 0.f;
    for (int c = 0; c < 64; ++c) {
        f32x4 ro = *(const f32x4*)&RoS[c * 64 + tr * 4];  // d
        f32x4 wb = *(const f32x4*)&Wb[c * 64 + tc * 4];   // b
#pragma unroll
        for (int i = 0; i < 4; ++i)
#pragma unroll
            for (int j = 0; j < 4; ++j) a1[i][j] += ro[i] * wb[j];
    }
#pragma unroll
    for (int i = 0; i < 4; ++i)
#pragma unroll
        for (int j = 0; j < 4; ++j) UdT[(tc * 4 + j) * 68 + tr * 4 + i] = a1[i][j];
    __syncthreads();
    float a2[4][4];
#pragma unroll
    for (int i = 0; i < 4; ++i)
#pragma unroll
        for (int j = 0; j < 4; ++j) a2[i][j] = 0.f;
    for (int b = 0; b < 64; ++b) {
        f32x4 ri = *(const f32x4*)&RiTs[b * 64 + tc * 4];  // a
        f32x4 ud = *(const f32x4*)&UdT[b * 68 + tr * 4];   // d
#pragma unroll
        for (int ai = 0; ai < 4; ++ai)
#pragma unroll
            for (int dj = 0; dj < 4; ++dj) a2[ai][dj] += ri[ai] * ud[dj];
    }
#pragma unroll
    for (int dj = 0; dj < 4; ++dj) {
        u16x4 o;
#pragma unroll
        for (int ai = 0; ai < 4; ++ai) o[ai] = f2bf(a2[ai][dj]);
        *(u16x4*)&Ct[(size_t)(r * 64 + tr * 4 + dj) * IN_F + s * 64 + tc * 4] = o;
    }
}

// ---------------- pass 5: Mt[j][k] = Ct[pout[j]][pin[k]] ----------------
__global__ __launch_bounds__(256) void k_permM(const u16* __restrict__ Ct,
                                               const int* __restrict__ pout,
                                               const int* __restrict__ pin,
                                               u16* __restrict__ Mt) {
    __shared__ u16 row[4096];
    int j = blockIdx.x;
    int t = threadIdx.x;
    const u16* sr = Ct + (size_t)pout[j] * IN_F;
#pragma unroll
    for (int e = 0; e < 16; ++e) row[e * 256 + t] = sr[e * 256 + t];
    __syncthreads();
    u16* dr = Mt + (size_t)j * IN_F;
#pragma unroll
    for (int e = 0; e < 16; ++e) {
        int k = e * 256 + t;
        dr[k] = row[pin[k]];
    }
}

// ---------------- pass 6: bias_final[j] = bias'[pout[j]] ----------------
__global__ void k_bias_perm(const float* __restrict__ bias_prime, const int* __restrict__ pout,
                            float* __restrict__ bias_final) {
    int j = blockIdx.x * 256 + threadIdx.x;
    if (j < OUT_F) bias_final[j] = bias_prime[pout[j]];
}

// ---------------- pass 7: x -> bf16 ----------------
__global__ __launch_bounds__(256) void k_xcast(const float* __restrict__ x,
                                               u16* __restrict__ xb) {
    size_t idx = ((size_t)blockIdx.x * 256 + threadIdx.x) * 8;
    const f32x4* xp = (const f32x4*)(x + idx);
    f32x4 a = xp[0], b = xp[1];
    union { short8 v; u16 s[8]; } o;
    o.s[0] = f2bf(a[0]); o.s[1] = f2bf(a[1]); o.s[2] = f2bf(a[2]); o.s[3] = f2bf(a[3]);
    o.s[4] = f2bf(b[0]); o.s[5] = f2bf(b[1]); o.s[6] = f2bf(b[2]); o.s[7] = f2bf(b[3]);
    *(short8*)(xb + idx) = o.v;
}

// ---------------- pass 8: out = xb @ Mt^T + bias ----------------
// 256x256 tile, BK=32, 8 waves (2Mx4N), 4 LDS buffers (128 KiB), 3-tile-deep
// counted-vmcnt prefetch, XOR-swizzled LDS (pre-swizzled global source), setprio.
__global__ __launch_bounds__(512, 2) void k_gemm(const u16* __restrict__ A,   // [8192][4096]
                                                 const u16* __restrict__ Bt,  // [4096][4096] N-major
                                                 const float* __restrict__ bias,
                                                 float* __restrict__ out) {
    __shared__ __align__(16) u16 lds[65536];   // 128 KiB: buf b at b*16384 (A:8192, B:8192 u16)
    const int t = threadIdx.x;
    const int lane = t & 63;
    const int wid = t >> 6;
    const int wr = wid >> 2, wc = wid & 3;

    int flat = blockIdx.y * gridDim.x + blockIdx.x;  // 0..511
    int swz  = (flat & 7) * 64 + (flat >> 3);        // XCD-contiguous work chunks
    int bm = swz >> 4;                               // 0..31
    int bn = swz & 15;                               // 0..15

    // staging: thread t handles 16B chunk ci = q*512+t; row=ci>>2, stored slot=ci&3,
    // source k-slot = slot ^ ((row>>1)&3)  (inverse-swizzled source, linear LDS dest)
    const int srow = t >> 2;                          // 0..127
    const int sks  = (t & 3) ^ ((t >> 3) & 3);
    const u16* sA0 = A  + (size_t)(bm * 256 + srow) * IN_F + sks * 8;
    const u16* sA1 = sA0 + (size_t)128 * IN_F;
    const u16* sB0 = Bt + (size_t)(bn * 256 + srow) * IN_F + sks * 8;
    const u16* sB1 = sB0 + (size_t)128 * IN_F;
    u16* dA = lds + t * 8;            // + buf*16384 (A region)
    u16* dB = lds + 8192 + t * 8;     // + buf*16384 (B region)

    // fragment read offsets (swizzled): byte slot = row*4 + (kg ^ ((row>>1)&3))
    const int frow = lane & 15;
    const int kg = lane >> 4;
    const int swzr = kg ^ ((frow >> 1) & 3);          // (row>>1)&3 == (frow>>1)&3 for all frags
    const int aoff = (wr * 128 + frow) * 32 + swzr * 8;           // u16 units
    const int boff = 8192 + (wc * 64 + frow) * 32 + swzr * 8;

    f32x4 acc[8][4];
#pragma unroll
    for (int m = 0; m < 8; ++m)
#pragma unroll
        for (int n = 0; n < 4; ++n) acc[m][n] = f32x4{0.f, 0.f, 0.f, 0.f};

    // prologue: stage tiles 0,1,2 (12 loads in flight)
#pragma unroll
    for (int p = 0; p < 3; ++p) {
        int off = p * 32;
        int bb = p * 16384;
        gload16(sA0 + off, dA + bb); gload16(sA1 + off, dA + bb + 4096);
        gload16(sB0 + off, dB + bb); gload16(sB1 + off, dB + bb + 4096);
    }
    asm volatile("s_waitcnt vmcnt(8)" ::: "memory");   // tile 0 landed
    __builtin_amdgcn_s_barrier();

    for (int t4 = 0; t4 < 128; t4 += 4) {
#pragma unroll
        for (int u = 0; u < 4; ++u) {
            const int kt = t4 + u;
            const u16* base = lds + u * 16384;
            short8 af[8], bf[4];
            const u16* pa = base + aoff;
            const u16* pb = base + boff;
#pragma unroll
            for (int m = 0; m < 8; ++m) af[m] = *(const short8*)(pa + m * 512);
#pragma unroll
            for (int n = 0; n < 4; ++n) bf[n] = *(const short8*)(pb + n * 512);
            // prefetch tile kt+3 into buf (kt+3)&3 (that buf's reads finished last iter)
            {
                int ts = kt + 3;
                int tsc = ts < 128 ? ts : 124;       // tail: dummy (never-read) loads keep vmcnt uniform
                int off = tsc * 32;
                int bb = ((kt + 3) & 3) * 16384;
                gload16(sA0 + off, dA + bb); gload16(sA1 + off, dA + bb + 4096);
                gload16(sB0 + off, dB + bb); gload16(sB1 + off, dB + bb + 4096);
            }
            __builtin_amdgcn_s_setprio(1);
#pragma unroll
            for (int m = 0; m < 8; ++m)
#pragma unroll
                for (int n = 0; n < 4; ++n)
                    acc[m][n] = __builtin_amdgcn_mfma_f32_16x16x32_bf16(af[m], bf[n], acc[m][n], 0, 0, 0);
            __builtin_amdgcn_s_setprio(0);
            asm volatile("s_waitcnt vmcnt(8)" ::: "memory");  // tile kt+1 landed; 8 stay in flight
            __builtin_amdgcn_s_barrier();
        }
    }
    asm volatile("s_waitcnt vmcnt(0)" ::: "memory");   // drain dummies before LDS dealloc

    const int col0 = bn * 256 + wc * 64 + frow;
    const int row0 = bm * 256 + wr * 128 + kg * 4;
    float bv[4];
#pragma unroll
    for (int n = 0; n < 4; ++n) bv[n] = bias[col0 + n * 16];
#pragma unroll
    for (int m = 0; m < 8; ++m)
#pragma unroll
        for (int n = 0; n < 4; ++n)
#pragma unroll
            for (int i = 0; i < 4; ++i)
                out[(size_t)(row0 + m * 16 + i) * OUT_F + col0 + n * 16] = acc[m][n][i] + bv[n];
}

extern "C" void kernel_launch(void* const* d_in, const int* in_sizes, int n_in,
                              void* d_out, int out_size, void* d_ws, size_t ws_size,
                              hipStream_t stream) {
    (void)in_sizes; (void)n_in; (void)out_size; (void)ws_size;
    const float* x    = (const float*)d_in[0];
    const float* Ro   = (const float*)d_in[1];
    const float* Ri   = (const float*)d_in[2];
    const float* W    = (const float*)d_in[3];
    const float* bias = (const float*)d_in[4];
    const int* perm_in_inv = (const int*)d_in[5];
    const int* perm_out    = (const int*)d_in[6];
    float* out = (float*)d_out;

    char* ws = (char*)d_ws;
    float* Rout   = (float*)(ws);                               // 1 MiB
    float* RinT   = (float*)(ws + (1ull << 20));                // 1 MiB
    int*   pin    = (int*)(ws + (2ull << 20));                  // 16 KiB
    float* bprime = (float*)(ws + (2ull << 20) + (1 << 16));
    float* bfinal = (float*)(ws + (2ull << 20) + (2 << 16));
    u16*   Mt     = (u16*)(ws + (4ull << 20));                  // 32 MiB
    u16*   Ct     = (u16*)(ws + (36ull << 20));                 // 32 MiB
    u16*   xb     = (u16*)(ws + (36ull << 20));                 // 64 MiB, aliases Ct (Ct consumed by permM before xcast)

    k_inv_perm<<<16, 256, 0, stream>>>(perm_in_inv, pin);
    k_cayley<<<128, 256, 0, stream>>>(Ro, Ri, Rout, RinT);
    k_bias_rot<<<64, 64, 0, stream>>>(bias, Rout, bprime);
    k_fold<<<dim3(64, 64), 256, 0, stream>>>(W, RinT, Rout, Ct);
    k_permM<<<4096, 256, 0, stream>>>(Ct, perm_out, pin, Mt);
    k_bias_perm<<<16, 256, 0, stream>>>(bprime, perm_out, bfinal);
    k_xcast<<<16384, 256, 0, stream>>>(x, xb);
    k_gemm<<<dim3(16, 32), 512, 0, stream>>>(xb, Mt, bfinal, out);
}

// Round 3
// 333.933 us; speedup vs baseline: 2.0170x; 1.1060x over previous
//
#include <hip/hip_runtime.h>
#include <stdint.h>

#define IN_F 4096
#define OUT_F 4096
#define NTRI 2016

typedef unsigned short u16;
typedef __attribute__((ext_vector_type(8))) short short8;
typedef __attribute__((ext_vector_type(4))) float f32x4;
typedef __attribute__((ext_vector_type(4))) unsigned short u16x4;

__device__ __forceinline__ u16 f2bf(float f) {
    uint32_t u = __builtin_bit_cast(uint32_t, f);
    u = (u + 0x7FFFu + ((u >> 16) & 1u)) >> 16;   // round-to-nearest-even
    return (u16)u;
}

__device__ __forceinline__ void gload16(const void* g, void* l) {
    __builtin_amdgcn_global_load_lds((__attribute__((address_space(1))) void*)g,
                                     (__attribute__((address_space(3))) void*)l,
                                     16, 0, 0);
}

#define FENCE() asm volatile("" ::: "memory")

// ---------------- pass 1: invert both permutations ----------------
__global__ void k_inv_perm(const int* __restrict__ perm_in_inv,
                           const int* __restrict__ perm_out,
                           int* __restrict__ pin, int* __restrict__ pinv_out) {
    int i = blockIdx.x * 256 + threadIdx.x;
    if (i < IN_F) {
        pin[perm_in_inv[i]] = i;       // pin = perm_in
        pinv_out[perm_out[i]] = i;     // pinv_out = perm_out^{-1}
    }
}

// ---------------- pass 2: Cayley-Neumann, 4x4 register-blocked ----------------
// blocks 0..63  -> Rout[b] f32 row-major  +  QT16[b][d][c] = R[c][d] (bf16, transposed)
// blocks 64..127-> P16[b-64][a][c] = R[a][c] (bf16 row-major)
__global__ __launch_bounds__(256) void k_cayley(const float* __restrict__ Ro,
                                                const float* __restrict__ Ri,
                                                float* __restrict__ Rout,
                                                u16* __restrict__ QT16,
                                                u16* __restrict__ P16) {
    __shared__ __align__(16) float Qs[64 * 64];
    __shared__ __align__(16) float Ps[64 * 68];
    __shared__ __align__(16) float Ts[64 * 68];
    int b = blockIdx.x;
    const float* vec = (b < 64) ? (Ro + (size_t)b * NTRI) : (Ri + (size_t)(b - 64) * NTRI);
    int t = threadIdx.x;
    int tr = t >> 4, tc = t & 15;
#pragma unroll
    for (int e = 0; e < 16; ++e) {
        int el = e * 256 + t;
        int i = el >> 6, j = el & 63;
        float q = 0.f;
        if (i < j) q =  vec[i * 63 - (i * (i - 1)) / 2 + (j - i - 1)];
        if (i > j) q = -vec[j * 63 - (j * (j - 1)) / 2 + (i - j - 1)];
        Qs[el] = q;
    }
    __syncthreads();
    float a2[4][4], a3[4][4], a4[4][4];
#pragma unroll
    for (int i = 0; i < 4; ++i)
#pragma unroll
        for (int j = 0; j < 4; ++j) { a2[i][j] = 0.f; a3[i][j] = 0.f; a4[i][j] = 0.f; }
    for (int k = 0; k < 64; ++k) {
        f32x4 qa = *(const f32x4*)&Qs[k * 64 + tr * 4];
        f32x4 qb = *(const f32x4*)&Qs[k * 64 + tc * 4];
#pragma unroll
        for (int i = 0; i < 4; ++i)
#pragma unroll
            for (int j = 0; j < 4; ++j) a2[i][j] -= qa[i] * qb[j];
    }
#pragma unroll
    for (int i = 0; i < 4; ++i)
#pragma unroll
        for (int j = 0; j < 4; ++j) Ps[(tr * 4 + i) * 68 + tc * 4 + j] = a2[i][j];
    __syncthreads();
    for (int k = 0; k < 64; ++k) {
        f32x4 pa = *(const f32x4*)&Ps[k * 68 + tr * 4];
        f32x4 qb = *(const f32x4*)&Qs[k * 64 + tc * 4];
#pragma unroll
        for (int i = 0; i < 4; ++i)
#pragma unroll
            for (int j = 0; j < 4; ++j) a3[i][j] += pa[i] * qb[j];
    }
#pragma unroll
    for (int i = 0; i < 4; ++i)
#pragma unroll
        for (int j = 0; j < 4; ++j) Ts[(tc * 4 + j) * 68 + tr * 4 + i] = -a3[i][j];  // Ts[k][i]=Q3[k][i]
    __syncthreads();
    for (int k = 0; k < 64; ++k) {
        f32x4 ta = *(const f32x4*)&Ts[k * 68 + tr * 4];
        f32x4 qb = *(const f32x4*)&Qs[k * 64 + tc * 4];
#pragma unroll
        for (int i = 0; i < 4; ++i)
#pragma unroll
            for (int j = 0; j < 4; ++j) a4[i][j] -= ta[i] * qb[j];
    }
    if (b < 64) {
        float* dst = Rout + (size_t)b * 4096;
        u16* qt = QT16 + (size_t)b * 4096;
#pragma unroll
        for (int i = 0; i < 4; ++i) {
            int gi = tr * 4 + i;
            f32x4 q4 = *(const f32x4*)&Qs[gi * 64 + tc * 4];
            f32x4 o;
#pragma unroll
            for (int j = 0; j < 4; ++j) {
                int gj = tc * 4 + j;
                o[j] = 2.f * (q4[j] + a2[i][j] + a3[i][j] + a4[i][j]) + ((gi == gj) ? 1.f : 0.f);
            }
            *(f32x4*)&dst[gi * 64 + tc * 4] = o;
#pragma unroll
            for (int j = 0; j < 4; ++j) qt[(tc * 4 + j) * 64 + gi] = f2bf(o[j]);  // QT[d][c]=R[c][d]
        }
    } else {
        u16* p = P16 + (size_t)(b - 64) * 4096;
#pragma unroll
        for (int i = 0; i < 4; ++i) {
            int gi = tr * 4 + i;
            f32x4 q4 = *(const f32x4*)&Qs[gi * 64 + tc * 4];
            u16x4 pk;
#pragma unroll
            for (int j = 0; j < 4; ++j) {
                int gj = tc * 4 + j;
                float v = 2.f * (q4[j] + a2[i][j] + a3[i][j] + a4[i][j]) + ((gi == gj) ? 1.f : 0.f);
                pk[j] = f2bf(v);
            }
            *(u16x4*)&p[gi * 64 + tc * 4] = pk;
        }
    }
}

// ---------------- pass 3: bias' = bias . R_out_bd ----------------
__global__ void k_bias_rot(const float* __restrict__ bias, const float* __restrict__ Rout,
                           float* __restrict__ bias_prime) {
    int r = blockIdx.x;
    int d = threadIdx.x;
    const float* Rb = Rout + (size_t)r * 4096;
    float s = 0.f;
    for (int c = 0; c < 64; ++c) s += bias[r * 64 + c] * Rb[c * 64 + d];
    bias_prime[r * 64 + d] = s;
}

// ---------------- pass 4: fused MFMA fold ----------------
// Per block (s, br): W-tile 128x64 -> mm1 U = W * P^T -> LDS (transposed, swizzled)
//                    -> mm2 Ct = Q^T * U, written row-permuted: Ctp[pinv_out[o]][s*64+i]
__global__ __launch_bounds__(256) void k_fold(const float* __restrict__ W,
                                              const u16* __restrict__ P16,
                                              const u16* __restrict__ QT16,
                                              const int* __restrict__ pinv_out,
                                              u16* __restrict__ Ctp) {
    __shared__ __align__(16) u16 Wst[128 * 64];   // swizzled bf16 W tile
    __shared__ __align__(16) u16 Ut[64 * 128];    // Ut[i][c] swizzled
    const int s = blockIdx.x;
    const int br = blockIdx.y;
    const int t = threadIdx.x;
    const int lane = t & 63;
    const int w = t >> 6;
    const int fl = lane & 15;
    const int kg = lane >> 4;

    // mm1 B-operand (P rows) from global (L3-resident), issue early
    short8 bfP[4][2];
    const u16* Pbase = P16 + (size_t)s * 4096;
#pragma unroll
    for (int nf = 0; nf < 4; ++nf)
#pragma unroll
        for (int kk = 0; kk < 2; ++kk)
            bfP[nf][kk] = *(const short8*)(Pbase + (nf * 16 + fl) * 64 + kk * 32 + kg * 8);

    // stage W tile -> bf16, XOR-swizzled (slot ^ (row&7))
#pragma unroll
    for (int q = 0; q < 4; ++q) {
        int ci = q * 256 + t;
        int row = ci >> 3, slot = ci & 7;
        const float* src = W + (size_t)(br * 128 + row) * IN_F + s * 64 + slot * 8;
        f32x4 v0 = *(const f32x4*)src;
        f32x4 v1 = *(const f32x4*)(src + 4);
        union { short8 v; u16 e[8]; } cv;
        cv.e[0] = f2bf(v0[0]); cv.e[1] = f2bf(v0[1]); cv.e[2] = f2bf(v0[2]); cv.e[3] = f2bf(v0[3]);
        cv.e[4] = f2bf(v1[0]); cv.e[5] = f2bf(v1[1]); cv.e[6] = f2bf(v1[2]); cv.e[7] = f2bf(v1[3]);
        *(short8*)&Wst[row * 64 + (slot ^ (row & 7)) * 8] = cv.v;
    }
    __syncthreads();

    // mm1: per wave rows w*32..w*32+31 of U[c][i]
    f32x4 acc1[2][4];
#pragma unroll
    for (int mf = 0; mf < 2; ++mf)
#pragma unroll
        for (int nf = 0; nf < 4; ++nf) acc1[mf][nf] = f32x4{0.f, 0.f, 0.f, 0.f};
#pragma unroll
    for (int mf = 0; mf < 2; ++mf) {
        int row = w * 32 + mf * 16 + fl;
#pragma unroll
        for (int kk = 0; kk < 2; ++kk) {
            short8 a = *(const short8*)&Wst[row * 64 + ((kk * 4 + kg) ^ (row & 7)) * 8];
#pragma unroll
            for (int nf = 0; nf < 4; ++nf)
                acc1[mf][nf] = __builtin_amdgcn_mfma_f32_16x16x32_bf16(a, bfP[nf][kk], acc1[mf][nf], 0, 0, 0);
        }
    }
    // write Ut[i][c] (transposed), swizzled at 16B-slot granularity, b64 chunks
#pragma unroll
    for (int mf = 0; mf < 2; ++mf)
#pragma unroll
        for (int nf = 0; nf < 4; ++nf) {
            int i = nf * 16 + fl;
            int c = w * 32 + mf * 16 + kg * 4;
            u16x4 pk;
#pragma unroll
            for (int reg = 0; reg < 4; ++reg) pk[reg] = f2bf(acc1[mf][nf][reg]);
            int slot = c >> 3, half = (c >> 2) & 1;
            *(u16x4*)&Ut[i * 128 + ((slot ^ (i & 7)) << 3) + (half << 2)] = pk;
        }
    __syncthreads();

    // mm2: Ct rows (this wave: rows w*32..w*32+31 of the 128-row tile)
    const int rbl = w >> 1;                 // which r-block of the two
    const int r_g = br * 2 + rbl;
    short8 aQ[2][2];
#pragma unroll
    for (int mf2 = 0; mf2 < 2; ++mf2) {
        int d = (w & 1) * 32 + mf2 * 16 + fl;
#pragma unroll
        for (int kk = 0; kk < 2; ++kk)
            aQ[mf2][kk] = *(const short8*)(QT16 + (size_t)r_g * 4096 + d * 64 + kk * 32 + kg * 8);
    }
    f32x4 acc2[2][4];
#pragma unroll
    for (int mf2 = 0; mf2 < 2; ++mf2)
#pragma unroll
        for (int nf = 0; nf < 4; ++nf) acc2[mf2][nf] = f32x4{0.f, 0.f, 0.f, 0.f};
#pragma unroll
    for (int kk = 0; kk < 2; ++kk)
#pragma unroll
        for (int nf = 0; nf < 4; ++nf) {
            int i = nf * 16 + fl;
            int slot = rbl * 8 + kk * 4 + kg;
            short8 bu = *(const short8*)&Ut[i * 128 + ((slot ^ (i & 7)) << 3)];
#pragma unroll
            for (int mf2 = 0; mf2 < 2; ++mf2)
                acc2[mf2][nf] = __builtin_amdgcn_mfma_f32_16x16x32_bf16(aQ[mf2][kk], bu, acc2[mf2][nf], 0, 0, 0);
        }
    // epilogue: row-permuted write
#pragma unroll
    for (int mf2 = 0; mf2 < 2; ++mf2)
#pragma unroll
        for (int reg = 0; reg < 4; ++reg) {
            int o_g = br * 128 + w * 32 + mf2 * 16 + kg * 4 + reg;
            int j = pinv_out[o_g];
            u16* dst = Ctp + (size_t)j * IN_F + s * 64;
#pragma unroll
            for (int nf = 0; nf < 4; ++nf)
                dst[nf * 16 + fl] = f2bf(acc2[mf2][nf][reg]);
        }
}

// ---------------- pass 5: Mt[j][k] = Ctp[j][pin[k]] ----------------
__global__ __launch_bounds__(256) void k_permM(const u16* __restrict__ Ctp,
                                               const int* __restrict__ pin,
                                               u16* __restrict__ Mt) {
    __shared__ u16 row[4096];
    int j = blockIdx.x;
    int t = threadIdx.x;
    const u16* sr = Ctp + (size_t)j * IN_F;
#pragma unroll
    for (int e = 0; e < 16; ++e) row[e * 256 + t] = sr[e * 256 + t];
    __syncthreads();
    u16* dr = Mt + (size_t)j * IN_F;
#pragma unroll
    for (int e = 0; e < 16; ++e) {
        int k = e * 256 + t;
        dr[k] = row[pin[k]];
    }
}

// ---------------- pass 6: bias_final[j] = bias'[pout[j]] ----------------
__global__ void k_bias_perm(const float* __restrict__ bias_prime, const int* __restrict__ pout,
                            float* __restrict__ bias_final) {
    int j = blockIdx.x * 256 + threadIdx.x;
    if (j < OUT_F) bias_final[j] = bias_prime[pout[j]];
}

// ---------------- pass 7: x -> bf16 ----------------
__global__ __launch_bounds__(256) void k_xcast(const float* __restrict__ x,
                                               u16* __restrict__ xb) {
    size_t idx = ((size_t)blockIdx.x * 256 + threadIdx.x) * 8;
    const f32x4* xp = (const f32x4*)(x + idx);
    f32x4 a = xp[0], b = xp[1];
    union { short8 v; u16 s[8]; } o;
    o.s[0] = f2bf(a[0]); o.s[1] = f2bf(a[1]); o.s[2] = f2bf(a[2]); o.s[3] = f2bf(a[3]);
    o.s[4] = f2bf(b[0]); o.s[5] = f2bf(b[1]); o.s[6] = f2bf(b[2]); o.s[7] = f2bf(b[3]);
    *(short8*)(xb + idx) = o.v;
}

// ---------------- pass 8: out = xb @ Mt^T + bias (2-phase-per-slot pipeline) --------
__global__ __launch_bounds__(512, 2) void k_gemm(const u16* __restrict__ A,   // [8192][4096]
                                                 const u16* __restrict__ Bt,  // [4096][4096] N-major
                                                 const float* __restrict__ bias,
                                                 float* __restrict__ out) {
    __shared__ __align__(16) u16 lds[65536];   // 4 slots x 16384 u16 (A:8192 + B:8192)
    const int t = threadIdx.x;
    const int lane = t & 63;
    const int wid = t >> 6;
    const int wr = wid >> 2, wc = wid & 3;

    int flat = blockIdx.y * gridDim.x + blockIdx.x;  // 0..511
    int swz  = (flat & 7) * 64 + (flat >> 3);        // XCD-contiguous chunks (512%8==0)
    int bm = swz >> 4;                               // 0..31
    int bn = swz & 15;                               // 0..15

    const int srow = t >> 2;
    const int sks  = (t & 3) ^ ((t >> 3) & 3);       // inverse-swizzled source k-slot
    const u16* sA0 = A  + (size_t)(bm * 256 + srow) * IN_F + sks * 8;
    const u16* sA1 = sA0 + (size_t)128 * IN_F;
    const u16* sB0 = Bt + (size_t)(bn * 256 + srow) * IN_F + sks * 8;
    const u16* sB1 = sB0 + (size_t)128 * IN_F;
    u16* dA = lds + t * 8;
    u16* dB = lds + 8192 + t * 8;

    const int frow = lane & 15;
    const int kg = lane >> 4;
    const int swzr = kg ^ ((frow >> 1) & 3);
    const int aoff = (wr * 128 + frow) * 32 + swzr * 8;
    const int boff = 8192 + (wc * 64 + frow) * 32 + swzr * 8;

    f32x4 acc[8][4];
#pragma unroll
    for (int m = 0; m < 8; ++m)
#pragma unroll
        for (int n = 0; n < 4; ++n) acc[m][n] = f32x4{0.f, 0.f, 0.f, 0.f};

    // prologue: stage slots 0,1,2 (12 loads in flight)
#pragma unroll
    for (int p = 0; p < 3; ++p) {
        int off = p * 32;
        int bb = p * 16384;
        gload16(sA0 + off, dA + bb); gload16(sA1 + off, dA + bb + 4096);
        gload16(sB0 + off, dB + bb); gload16(sB1 + off, dB + bb + 4096);
    }
    asm volatile("s_waitcnt vmcnt(8)" ::: "memory");   // slot 0 landed
    __builtin_amdgcn_s_barrier();
    FENCE();

    for (int t4 = 0; t4 < 128; t4 += 4) {
#pragma unroll
        for (int u = 0; u < 4; ++u) {
            const int kt = t4 + u;
            const u16* pa = lds + u * 16384 + aoff;
            const u16* pb = lds + u * 16384 + boff;
            int ts = kt + 3;
            int tsc = ts < 128 ? ts : 124;            // tail dummies keep vmcnt uniform
            int off = tsc * 32;
            int bb = ((kt + 3) & 3) * 16384;
            // ---- phase A: m 0..3 ----
            short8 af0[4], bfr[4];
#pragma unroll
            for (int m = 0; m < 4; ++m) af0[m] = *(const short8*)(pa + m * 512);
#pragma unroll
            for (int n = 0; n < 4; ++n) bfr[n] = *(const short8*)(pb + n * 512);
            gload16(sA0 + off, dA + bb); gload16(sA1 + off, dA + bb + 4096);
            FENCE();
            __builtin_amdgcn_s_barrier();
            FENCE();
            __builtin_amdgcn_s_setprio(1);
#pragma unroll
            for (int m = 0; m < 4; ++m)
#pragma unroll
                for (int n = 0; n < 4; ++n)
                    acc[m][n] = __builtin_amdgcn_mfma_f32_16x16x32_bf16(af0[m], bfr[n], acc[m][n], 0, 0, 0);
            __builtin_amdgcn_s_setprio(0);
            FENCE();
            __builtin_amdgcn_s_barrier();
            FENCE();
            // ---- phase B: m 4..7 ----
            short8 af1[4];
#pragma unroll
            for (int m = 0; m < 4; ++m) af1[m] = *(const short8*)(pa + (m + 4) * 512);
            gload16(sB0 + off, dB + bb); gload16(sB1 + off, dB + bb + 4096);
            FENCE();
            __builtin_amdgcn_s_barrier();
            FENCE();
            __builtin_amdgcn_s_setprio(1);
#pragma unroll
            for (int m = 0; m < 4; ++m)
#pragma unroll
                for (int n = 0; n < 4; ++n)
                    acc[m + 4][n] = __builtin_amdgcn_mfma_f32_16x16x32_bf16(af1[m], bfr[n], acc[m + 4][n], 0, 0, 0);
            __builtin_amdgcn_s_setprio(0);
            asm volatile("s_waitcnt vmcnt(8)" ::: "memory");  // slot kt+1 landed; 8 stay in flight
            __builtin_amdgcn_s_barrier();
            FENCE();
        }
    }
    asm volatile("s_waitcnt vmcnt(0)" ::: "memory");   // drain tail dummies

    const int col0 = bn * 256 + wc * 64 + frow;
    const int row0 = bm * 256 + wr * 128 + kg * 4;
    float bv[4];
#pragma unroll
    for (int n = 0; n < 4; ++n) bv[n] = bias[col0 + n * 16];
#pragma unroll
    for (int m = 0; m < 8; ++m)
#pragma unroll
        for (int n = 0; n < 4; ++n)
#pragma unroll
            for (int i = 0; i < 4; ++i)
                out[(size_t)(row0 + m * 16 + i) * OUT_F + col0 + n * 16] = acc[m][n][i] + bv[n];
}

extern "C" void kernel_launch(void* const* d_in, const int* in_sizes, int n_in,
                              void* d_out, int out_size, void* d_ws, size_t ws_size,
                              hipStream_t stream) {
    (void)in_sizes; (void)n_in; (void)out_size; (void)ws_size;
    const float* x    = (const float*)d_in[0];
    const float* Ro   = (const float*)d_in[1];
    const float* Ri   = (const float*)d_in[2];
    const float* W    = (const float*)d_in[3];
    const float* bias = (const float*)d_in[4];
    const int* perm_in_inv = (const int*)d_in[5];
    const int* perm_out    = (const int*)d_in[6];
    float* out = (float*)d_out;

    char* ws = (char*)d_ws;
    float* Rout   = (float*)(ws);                               // 1 MiB
    u16*   P16    = (u16*)(ws + (1ull << 20));                  // 512 KiB
    u16*   QT16   = (u16*)(ws + (1ull << 20) + (1 << 19));      // 512 KiB
    int*   pin    = (int*)(ws + (2ull << 20));                  // 16 KiB
    int*   pinvo  = (int*)(ws + (2ull << 20) + (1 << 16));
    float* bprime = (float*)(ws + (2ull << 20) + (2 << 16));
    float* bfinal = (float*)(ws + (2ull << 20) + (3 << 16));
    u16*   Mt     = (u16*)(ws + (4ull << 20));                  // 32 MiB
    u16*   xb     = (u16*)(ws + (36ull << 20));                 // 64 MiB
    u16*   Ctp    = (u16*)(ws + (36ull << 20));                 // 32 MiB, aliases xb (consumed by permM before xcast)

    k_inv_perm<<<16, 256, 0, stream>>>(perm_in_inv, perm_out, pin, pinvo);
    k_cayley<<<128, 256, 0, stream>>>(Ro, Ri, Rout, QT16, P16);
    k_bias_rot<<<64, 64, 0, stream>>>(bias, Rout, bprime);
    k_fold<<<dim3(64, 32), 256, 0, stream>>>(W, P16, QT16, pinvo, Ctp);
    k_permM<<<4096, 256, 0, stream>>>(Ctp, pin, Mt);
    k_bias_perm<<<16, 256, 0, stream>>>(bprime, perm_out, bfinal);
    k_xcast<<<16384, 256, 0, stream>>>(x, xb);
    k_gemm<<<dim3(16, 32), 512, 0, stream>>>(xb, Mt, bfinal, out);
}